// Round 9
// baseline (249.002 us; speedup 1.0000x reference)
//
#include <hip/hip_runtime.h>
#include <hip/hip_bf16.h>
#include <cstdint>

#define DEV __device__ __forceinline__

constexpr int B = 64, T = 1024, N = 512, D = 64, K = 80;

typedef __attribute__((ext_vector_type(8))) short bf16x8;
typedef __attribute__((ext_vector_type(4))) float f32x4;

DEV float fast_tanh(float x) {
    x = fminf(fmaxf(x, -15.f), 15.f);
    float e = __expf(2.f * x);
    return (e - 1.f) / (e + 1.f);
}

DEV unsigned short f2bf(float f) {
    unsigned int u = __float_as_uint(f);
    unsigned int r = (u + 0x7fffu + ((u >> 16) & 1u)) >> 16;
    return (unsigned short)r;
}
DEV float bf2f(unsigned short s) {
    return __uint_as_float(((unsigned int)s) << 16);
}

// Fragment-native tiled layout for all bf16 intermediate buffers.
// off(row,col) = ((row/16)*(S/8) + col/8)*128 + (row%16)*8 + (col%8)
// => a wave's MFMA fragment load (rows base+lr, cols c0+lg*8) is a single
//    contiguous 1KB segment. S8 = columns/8.
DEV size_t tix(size_t row, int col, int S8) {
    return (((row >> 4) * S8 + (size_t)(col >> 3)) << 7) + ((row & 15) << 3) + (col & 7);
}

#define MFMA(a, b, c) __builtin_amdgcn_mfma_f32_16x16x32_bf16((a), (b), (c), 0, 0, 0)

// ---------------------------------------------------------------------------
// Kernel A: M[b,t,:] = review[b,t,:] @ Wl, written as bf16 hi/lo pair (tiled)
__global__ __launch_bounds__(256) void k_matWl(const float* __restrict__ review,
                                               const float* __restrict__ Wl,
                                               unsigned short* __restrict__ Mhi,
                                               unsigned short* __restrict__ Mlo) {
    __shared__ float Wls[64][64];
    __shared__ float Rs[4][64];
    int tid = threadIdx.x;
    size_t base = (size_t)blockIdx.x * 256;
#pragma unroll
    for (int i = 0; i < 16; i++) { int e = tid + i * 256; Wls[e >> 6][e & 63] = Wl[e]; }
    Rs[tid >> 6][tid & 63] = review[base + tid];
    __syncthreads();
    int r = tid >> 6, c = tid & 63;
    float acc = 0.f;
#pragma unroll
    for (int d = 0; d < 64; d++) acc += Rs[r][d] * Wls[d][c];
    unsigned short h = f2bf(acc);
    size_t o = tix((size_t)blockIdx.x * 4 + r, c, 8);
    Mhi[o] = h;
    Mlo[o] = f2bf(acc - bf2f(h));
}

// ---------------------------------------------------------------------------
// Splitter: f32 -> bf16 hi/lo, elementwise, tiled-layout output (for post)
__global__ __launch_bounds__(256) void k_split(const float* __restrict__ X,
                                               unsigned short* __restrict__ Xhi,
                                               unsigned short* __restrict__ Xlo,
                                               int n4) {
    int i = blockIdx.x * 256 + threadIdx.x;
    if (i >= n4) return;
    float4 v = *reinterpret_cast<const float4*>(X + (size_t)i * 4);
    ushort4 h, lo;
    h.x = f2bf(v.x); lo.x = f2bf(v.x - bf2f(h.x));
    h.y = f2bf(v.y); lo.y = f2bf(v.y - bf2f(h.y));
    h.z = f2bf(v.z); lo.z = f2bf(v.z - bf2f(h.z));
    h.w = f2bf(v.w); lo.w = f2bf(v.w - bf2f(h.w));
    size_t o = tix((size_t)(i >> 4), (i & 15) * 4, 8);   // row = i*4/64, col = (i*4)%64
    *reinterpret_cast<ushort4*>(Xhi + o) = h;
    *reinterpret_cast<ushort4*>(Xlo + o) = lo;
}

// ---------------------------------------------------------------------------
// Kernel B: proj[b,k,s] = sum_d W[k,d] * X[b,s,d], bf16 hi/lo pair, tiled
__global__ __launch_bounds__(256) void k_proj(const float* __restrict__ W,
                                              const float* __restrict__ X,
                                              unsigned short* __restrict__ Phi,
                                              unsigned short* __restrict__ Plo, int S) {
    __shared__ float Ws[80][64];
    __shared__ float Xs[64][65];
    int tid = threadIdx.x, tx = tid & 63, ty = tid >> 6;
    int b = blockIdx.y, s0 = blockIdx.x * 64;
#pragma unroll
    for (int i = 0; i < 20; i++) { int e = tid + i * 256; Ws[e >> 6][e & 63] = W[e]; }
    const float* Xp = X + ((size_t)b * S + s0) * 64;
#pragma unroll
    for (int i = 0; i < 16; i++) { int e = tid + i * 256; Xs[e >> 6][e & 63] = Xp[e]; }
    __syncthreads();
    float acc[20];
#pragma unroll
    for (int kk = 0; kk < 20; kk++) acc[kk] = 0.f;
    for (int d = 0; d < 64; d += 4) {
        float x0 = Xs[tx][d], x1 = Xs[tx][d + 1], x2 = Xs[tx][d + 2], x3 = Xs[tx][d + 3];
#pragma unroll
        for (int kk = 0; kk < 20; kk++) {
            const float4 w = *reinterpret_cast<const float4*>(&Ws[ty * 20 + kk][d]);
            acc[kk] += w.x * x0 + w.y * x1 + w.z * x2 + w.w * x3;
        }
    }
    int S8 = S >> 3;
#pragma unroll
    for (int kk = 0; kk < 20; kk++) {
        size_t idx = tix((size_t)b * K + ty * 20 + kk, s0 + tx, S8);
        float v = acc[kk];
        unsigned short h = f2bf(v);
        Phi[idx] = h;
        Plo[idx] = f2bf(v - bf2f(h));
    }
}

// ---------------------------------------------------------------------------
// Fused HP v9: 256 thr = 4 waves. Each wave owns ALL FOUR 16-row n-slices
// (s=0..3) and a DISTINCT t-quarter (t0=(wv+4*it)*64, it<4). This removes
// the v6-v8 2x duplication where wave-pairs issued identical M/Rr panel
// loads: per-block loads 1152KB -> 576KB. Loop stays barrier-free (wave-
// private Lt buffer). End: 2-round LDS reduction tree + split epilogue.
__global__ __launch_bounds__(256) void k_hp_fused(
    const unsigned short* __restrict__ Mhi, const unsigned short* __restrict__ Mlo,
    const unsigned short* __restrict__ PsH, const unsigned short* __restrict__ PsL,
    const unsigned short* __restrict__ Rhi, const unsigned short* __restrict__ Rlo,
    const unsigned short* __restrict__ Phi, const unsigned short* __restrict__ Plo,
    const float* __restrict__ whp, float* __restrict__ logits_p) {
    __shared__ __align__(16) float smem[10240];          // 40,960 B
    typedef unsigned short LtArr[64][72];
    LtArr* Lt = reinterpret_cast<LtArr*>(smem);          // Lt[4][64][72] = 36,864 B
    float* redf = smem;                                  // reduce scratch (after loop)
    int b = blockIdx.x, nc0 = blockIdx.y * 64;
    int tid = threadIdx.x, l = tid & 63, wv = tid >> 6;
    int lr = l & 15, lg = l >> 4;

    // Preload A-operand (post rows for all four n-slices): loop-invariant.
    bf16x8 pah[4][2], pal[4][2];
#pragma unroll
    for (int s = 0; s < 4; s++)
#pragma unroll
        for (int c = 0; c < 2; c++) {
            size_t o = tix((size_t)b * N + nc0 + s * 16 + lr, c * 32 + lg * 8, 8);
            pah[s][c] = *reinterpret_cast<const bf16x8*>(PsH + o);
            pal[s][c] = *reinterpret_cast<const bf16x8*>(PsL + o);
        }

    f32x4 hp[4][5];
#pragma unroll
    for (int s = 0; s < 4; s++)
#pragma unroll
        for (int f = 0; f < 5; f++) hp[s][f] = (f32x4){0.f, 0.f, 0.f, 0.f};

    for (int it = 0; it < 4; it++) {
        int t0 = (wv + it * 4) * 64;
        // phase 1 (swapped operands): per tf, all 4 slices, tanh straight to LDS.
#pragma unroll
        for (int tf = 0; tf < 4; tf++) {
            size_t mrow = (size_t)b * T + t0 + tf * 16 + lr;
            size_t m0 = tix(mrow, lg * 8, 8), m1 = tix(mrow, 32 + lg * 8, 8);
            bf16x8 mh0 = *reinterpret_cast<const bf16x8*>(Mhi + m0);
            bf16x8 mh1 = *reinterpret_cast<const bf16x8*>(Mhi + m1);
            bf16x8 ml0 = *reinterpret_cast<const bf16x8*>(Mlo + m0);
            bf16x8 ml1 = *reinterpret_cast<const bf16x8*>(Mlo + m1);
#pragma unroll
            for (int s = 0; s < 4; s++) {
                f32x4 a = (f32x4){0.f, 0.f, 0.f, 0.f};
                a = MFMA(pah[s][0], mh0, a);
                a = MFMA(pah[s][0], ml0, a);
                a = MFMA(pal[s][0], mh0, a);
                a = MFMA(pah[s][1], mh1, a);
                a = MFMA(pah[s][1], ml1, a);
                a = MFMA(pal[s][1], mh1, a);
#pragma unroll
                for (int r = 0; r < 4; r++)
                    Lt[wv][s * 16 + lg * 4 + r][tf * 16 + lr] = f2bf(fast_tanh(a[r]));
            }
        }
        bf16x8 bt0[4], bt1[4];
#pragma unroll
        for (int s = 0; s < 4; s++) {
            bt0[s] = *reinterpret_cast<const bf16x8*>(&Lt[wv][s * 16 + lr][lg * 8]);
            bt1[s] = *reinterpret_cast<const bf16x8*>(&Lt[wv][s * 16 + lr][32 + lg * 8]);
        }
        // phase 2: hp[s][k] += Rr[k, t-tile] @ Lt[slice s]; Rr loads shared x4
#pragma unroll
        for (int kf = 0; kf < 5; kf++) {
            size_t krow = (size_t)b * K + kf * 16 + lr;
            size_t r0 = tix(krow, t0 + lg * 8, 128), r1 = tix(krow, t0 + 32 + lg * 8, 128);
            bf16x8 rh0 = *reinterpret_cast<const bf16x8*>(Rhi + r0);
            bf16x8 rh1 = *reinterpret_cast<const bf16x8*>(Rhi + r1);
            bf16x8 rl0 = *reinterpret_cast<const bf16x8*>(Rlo + r0);
            bf16x8 rl1 = *reinterpret_cast<const bf16x8*>(Rlo + r1);
#pragma unroll
            for (int s = 0; s < 4; s++) {
                hp[s][kf] = MFMA(rh0, bt0[s], hp[s][kf]);
                hp[s][kf] = MFMA(rl0, bt0[s], hp[s][kf]);
                hp[s][kf] = MFMA(rh1, bt1[s], hp[s][kf]);
                hp[s][kf] = MFMA(rl1, bt1[s], hp[s][kf]);
            }
        }
    }

    // Round 1: waves 2,3 dump all 20 f32x4; waves 0,1 accumulate.
    __syncthreads();
    if (wv >= 2) {
        float* reg = redf + (wv - 2) * 5120;
#pragma unroll
        for (int s = 0; s < 4; s++)
#pragma unroll
            for (int kf = 0; kf < 5; kf++)
                *reinterpret_cast<f32x4*>(&reg[(s * 5 + kf) * 256 + l * 4]) = hp[s][kf];
    }
    __syncthreads();
    if (wv < 2) {
        float* reg = redf + wv * 5120;
#pragma unroll
        for (int s = 0; s < 4; s++)
#pragma unroll
            for (int kf = 0; kf < 5; kf++)
                hp[s][kf] += *reinterpret_cast<f32x4*>(&reg[(s * 5 + kf) * 256 + l * 4]);
    }
    __syncthreads();
    // Round 2: wave0 dumps slices 2,3 (region A); wave1 dumps slices 0,1 (B).
    if (wv == 0) {
#pragma unroll
        for (int s = 2; s < 4; s++)
#pragma unroll
            for (int kf = 0; kf < 5; kf++)
                *reinterpret_cast<f32x4*>(&redf[((s - 2) * 5 + kf) * 256 + l * 4]) = hp[s][kf];
    } else if (wv == 1) {
#pragma unroll
        for (int s = 0; s < 2; s++)
#pragma unroll
            for (int kf = 0; kf < 5; kf++)
                *reinterpret_cast<f32x4*>(&redf[5120 + (s * 5 + kf) * 256 + l * 4]) = hp[s][kf];
    }
    __syncthreads();
    if (wv < 2) {
        // wave0 finalizes slices 0,1; wave1 finalizes slices 2,3.
#pragma unroll
        for (int j = 0; j < 2; j++) {
            int s = wv * 2 + j;
            f32x4 acc = hp[s][0];   // placeholder to keep indexing simple
#pragma unroll
            for (int kf = 0; kf < 5; kf++) {
                f32x4 other = (wv == 0)
                    ? *reinterpret_cast<f32x4*>(&redf[5120 + (s * 5 + kf) * 256 + l * 4])
                    : *reinterpret_cast<f32x4*>(&redf[((s - 2) * 5 + kf) * 256 + l * 4]);
                hp[s][kf] += other;
            }
            (void)acc;
            int n = nc0 + s * 16 + lr;
            float partial = 0.f;
#pragma unroll
            for (int kf = 0; kf < 5; kf++)
#pragma unroll
                for (int r = 0; r < 4; r++) {
                    int k = kf * 16 + lg * 4 + r;
                    size_t idx = tix((size_t)b * K + k, n, 64);
                    float pp = bf2f(Phi[idx]) + bf2f(Plo[idx]);
                    partial += whp[k] * fast_tanh(pp + hp[s][kf][r]);
                }
            partial += __shfl_xor(partial, 16);
            partial += __shfl_xor(partial, 32);
            if (lg == 0) logits_p[(size_t)b * N + n] = partial;
        }
    }
}

// ---------------------------------------------------------------------------
// Fused HR v9: 256 thr = 4 waves. Each wave owns ALL FOUR t-slices and a
// DISTINCT n-quarter (n0=(wv+4*it)*64, it<2): per-block loads 576KB -> 288KB
// (no duplicated Ps/Pp streams). Same end-reduction as HP v9.
__global__ __launch_bounds__(256) void k_hr_fused(
    const unsigned short* __restrict__ Mhi, const unsigned short* __restrict__ Mlo,
    const unsigned short* __restrict__ PsH, const unsigned short* __restrict__ PsL,
    const unsigned short* __restrict__ Phi, const unsigned short* __restrict__ Plo,
    const unsigned short* __restrict__ Rhi, const unsigned short* __restrict__ Rlo,
    const float* __restrict__ whr, float* __restrict__ logits_r) {
    __shared__ __align__(16) float smem[10240];
    typedef unsigned short LdArr[64][72];
    LdArr* Ld = reinterpret_cast<LdArr*>(smem);
    float* redf = smem;
    int b = blockIdx.x, tc0 = blockIdx.y * 64;
    int tid = threadIdx.x, l = tid & 63, wv = tid >> 6;
    int lr = l & 15, lg = l >> 4;

    // Preload A (M) fragments for all four t-slices: loop-invariant.
    bf16x8 mh0[4], mh1[4], ml0[4], ml1[4];
#pragma unroll
    for (int s = 0; s < 4; s++) {
        size_t mrow = (size_t)b * T + tc0 + s * 16 + lr;
        size_t m0 = tix(mrow, lg * 8, 8), m1 = tix(mrow, 32 + lg * 8, 8);
        mh0[s] = *reinterpret_cast<const bf16x8*>(Mhi + m0);
        mh1[s] = *reinterpret_cast<const bf16x8*>(Mhi + m1);
        ml0[s] = *reinterpret_cast<const bf16x8*>(Mlo + m0);
        ml1[s] = *reinterpret_cast<const bf16x8*>(Mlo + m1);
    }

    f32x4 hr[4][5];
#pragma unroll
    for (int s = 0; s < 4; s++)
#pragma unroll
        for (int f = 0; f < 5; f++) hr[s][f] = (f32x4){0.f, 0.f, 0.f, 0.f};

    for (int it = 0; it < 2; it++) {
        int n0 = (wv + it * 4) * 64;
#pragma unroll
        for (int nf = 0; nf < 4; nf++) {
            size_t prow = (size_t)b * N + n0 + nf * 16 + lr;
            size_t p0 = tix(prow, lg * 8, 8), p1 = tix(prow, 32 + lg * 8, 8);
            bf16x8 ph0 = *reinterpret_cast<const bf16x8*>(PsH + p0);
            bf16x8 ph1 = *reinterpret_cast<const bf16x8*>(PsH + p1);
            bf16x8 pl0 = *reinterpret_cast<const bf16x8*>(PsL + p0);
            bf16x8 pl1 = *reinterpret_cast<const bf16x8*>(PsL + p1);
#pragma unroll
            for (int s = 0; s < 4; s++) {
                f32x4 a = (f32x4){0.f, 0.f, 0.f, 0.f};
                a = MFMA(mh0[s], ph0, a);
                a = MFMA(mh0[s], pl0, a);
                a = MFMA(ml0[s], ph0, a);
                a = MFMA(mh1[s], ph1, a);
                a = MFMA(mh1[s], pl1, a);
                a = MFMA(ml1[s], ph1, a);
#pragma unroll
                for (int r = 0; r < 4; r++)
                    Ld[wv][s * 16 + lg * 4 + r][nf * 16 + lr] = f2bf(fast_tanh(a[r]));
            }
        }
        bf16x8 bt0[4], bt1[4];
#pragma unroll
        for (int s = 0; s < 4; s++) {
            bt0[s] = *reinterpret_cast<const bf16x8*>(&Ld[wv][s * 16 + lr][lg * 8]);
            bt1[s] = *reinterpret_cast<const bf16x8*>(&Ld[wv][s * 16 + lr][32 + lg * 8]);
        }
#pragma unroll
        for (int kf = 0; kf < 5; kf++) {
            size_t krow = (size_t)b * K + kf * 16 + lr;
            size_t q0 = tix(krow, n0 + lg * 8, 64), q1 = tix(krow, n0 + 32 + lg * 8, 64);
            bf16x8 qh0 = *reinterpret_cast<const bf16x8*>(Phi + q0);
            bf16x8 qh1 = *reinterpret_cast<const bf16x8*>(Phi + q1);
            bf16x8 ql0 = *reinterpret_cast<const bf16x8*>(Plo + q0);
            bf16x8 ql1 = *reinterpret_cast<const bf16x8*>(Plo + q1);
#pragma unroll
            for (int s = 0; s < 4; s++) {
                hr[s][kf] = MFMA(qh0, bt0[s], hr[s][kf]);
                hr[s][kf] = MFMA(ql0, bt0[s], hr[s][kf]);
                hr[s][kf] = MFMA(qh1, bt1[s], hr[s][kf]);
                hr[s][kf] = MFMA(ql1, bt1[s], hr[s][kf]);
            }
        }
    }

    // Round 1: waves 2,3 dump; waves 0,1 accumulate.
    __syncthreads();
    if (wv >= 2) {
        float* reg = redf + (wv - 2) * 5120;
#pragma unroll
        for (int s = 0; s < 4; s++)
#pragma unroll
            for (int kf = 0; kf < 5; kf++)
                *reinterpret_cast<f32x4*>(&reg[(s * 5 + kf) * 256 + l * 4]) = hr[s][kf];
    }
    __syncthreads();
    if (wv < 2) {
        float* reg = redf + wv * 5120;
#pragma unroll
        for (int s = 0; s < 4; s++)
#pragma unroll
            for (int kf = 0; kf < 5; kf++)
                hr[s][kf] += *reinterpret_cast<f32x4*>(&reg[(s * 5 + kf) * 256 + l * 4]);
    }
    __syncthreads();
    // Round 2: slice exchange between waves 0 and 1.
    if (wv == 0) {
#pragma unroll
        for (int s = 2; s < 4; s++)
#pragma unroll
            for (int kf = 0; kf < 5; kf++)
                *reinterpret_cast<f32x4*>(&redf[((s - 2) * 5 + kf) * 256 + l * 4]) = hr[s][kf];
    } else if (wv == 1) {
#pragma unroll
        for (int s = 0; s < 2; s++)
#pragma unroll
            for (int kf = 0; kf < 5; kf++)
                *reinterpret_cast<f32x4*>(&redf[5120 + (s * 5 + kf) * 256 + l * 4]) = hr[s][kf];
    }
    __syncthreads();
    if (wv < 2) {
#pragma unroll
        for (int j = 0; j < 2; j++) {
            int s = wv * 2 + j;
#pragma unroll
            for (int kf = 0; kf < 5; kf++) {
                f32x4 other = (wv == 0)
                    ? *reinterpret_cast<f32x4*>(&redf[5120 + (s * 5 + kf) * 256 + l * 4])
                    : *reinterpret_cast<f32x4*>(&redf[((s - 2) * 5 + kf) * 256 + l * 4]);
                hr[s][kf] += other;
            }
            int t = tc0 + s * 16 + lr;
            float partial = 0.f;
#pragma unroll
            for (int kf = 0; kf < 5; kf++)
#pragma unroll
                for (int r = 0; r < 4; r++) {
                    int k = kf * 16 + lg * 4 + r;
                    size_t idx = tix((size_t)b * K + k, t, 128);
                    float rr = bf2f(Rhi[idx]) + bf2f(Rlo[idx]);
                    partial += whr[k] * fast_tanh(rr + hr[s][kf][r]);
                }
            partial += __shfl_xor(partial, 16);
            partial += __shfl_xor(partial, 32);
            if (lg == 0) logits_r[(size_t)b * T + t] = partial;
        }
    }
}

// ---------------------------------------------------------------------------
// Zero the output buffer (for atomic pooled accumulation). grid = B*128/256.
__global__ __launch_bounds__(256) void k_zero(float* __restrict__ out) {
    out[(size_t)blockIdx.x * 256 + threadIdx.x] = 0.f;
}

// ---------------------------------------------------------------------------
// Kernel F/G: softmax over S, then out[b, off+d] += sum_{s in chunk} sm[s]*X[b,s,d].
__global__ __launch_bounds__(256) void k_softpool(const float* __restrict__ logits,
                                                  const float* __restrict__ X,
                                                  float* __restrict__ out, int S, int off) {
    __shared__ float sm[1024];
    __shared__ float red[256];
    int b = blockIdx.x, tid = threadIdx.x;
    int c0 = blockIdx.y * 128;
    for (int i = tid; i < S; i += 256) sm[i] = logits[(size_t)b * S + i];
    __syncthreads();
    float m = -1e30f;
    for (int i = tid; i < S; i += 256) m = fmaxf(m, sm[i]);
    red[tid] = m;
    __syncthreads();
    for (int s = 128; s > 0; s >>= 1) {
        if (tid < s) red[tid] = fmaxf(red[tid], red[tid + s]);
        __syncthreads();
    }
    float mx = red[0];
    __syncthreads();
    float psum = 0.f;
    for (int i = tid; i < S; i += 256) {
        float e = __expf(sm[i] - mx);
        sm[i] = e;
        psum += e;
    }
    red[tid] = psum;
    __syncthreads();
    for (int s = 128; s > 0; s >>= 1) {
        if (tid < s) red[tid] += red[tid + s];
        __syncthreads();
    }
    float inv = 1.f / red[0];
    __syncthreads();
    int d = tid & 63, g = tid >> 6;
    float acc = 0.f;
    for (int n = c0 + g; n < c0 + 128; n += 4) acc += sm[n] * X[((size_t)b * S + n) * 64 + d];
    red[tid] = acc * inv;
    __syncthreads();
    if (g == 0)
        atomicAdd(&out[(size_t)b * 128 + off + d],
                  red[d] + red[64 + d] + red[128 + d] + red[192 + d]);
}

// ---------------------------------------------------------------------------
extern "C" void kernel_launch(void* const* d_in, const int* in_sizes, int n_in,
                              void* d_out, int out_size, void* d_ws, size_t ws_size,
                              hipStream_t stream) {
    const float* review = (const float*)d_in[0];
    const float* post   = (const float*)d_in[1];
    const float* Wl     = (const float*)d_in[2];
    const float* Wr     = (const float*)d_in[3];
    const float* Wp     = (const float*)d_in[4];
    const float* whr    = (const float*)d_in[5];
    const float* whp    = (const float*)d_in[6];
    float* out = (float*)d_out;

    char* p = (char*)d_ws;
    unsigned short* Mhi = (unsigned short*)p;  p += (size_t)B * T * D * 2;
    unsigned short* Mlo = (unsigned short*)p;  p += (size_t)B * T * D * 2;
    unsigned short* PsH = (unsigned short*)p;  p += (size_t)B * N * D * 2;
    unsigned short* PsL = (unsigned short*)p;  p += (size_t)B * N * D * 2;
    unsigned short* Rhi = (unsigned short*)p;  p += (size_t)B * K * T * 2;
    unsigned short* Rlo = (unsigned short*)p;  p += (size_t)B * K * T * 2;
    unsigned short* Phi = (unsigned short*)p;  p += (size_t)B * K * N * 2;
    unsigned short* Plo = (unsigned short*)p;  p += (size_t)B * K * N * 2;
    float* logits_p = (float*)p;        p += (size_t)B * N * 4;
    float* logits_r = (float*)p;        p += (size_t)B * T * 4;

    k_matWl<<<dim3(B * T / 4), dim3(256), 0, stream>>>(review, Wl, Mhi, Mlo);
    k_split<<<dim3(B * N * D / 4 / 256), dim3(256), 0, stream>>>(post, PsH, PsL, B * N * D / 4);
    k_proj<<<dim3(T / 64, B), dim3(256), 0, stream>>>(Wr, review, Rhi, Rlo, T);
    k_proj<<<dim3(N / 64, B), dim3(256), 0, stream>>>(Wp, post, Phi, Plo, N);
    k_zero<<<dim3(B * 128 / 256), dim3(256), 0, stream>>>(out);
    k_hp_fused<<<dim3(B, N / 64), dim3(256), 0, stream>>>(Mhi, Mlo, PsH, PsL, Rhi, Rlo,
                                                          Phi, Plo, whp, logits_p);
    k_hr_fused<<<dim3(B, T / 64), dim3(256), 0, stream>>>(Mhi, Mlo, PsH, PsL, Phi, Plo,
                                                          Rhi, Rlo, whr, logits_r);
    k_softpool<<<dim3(B, N / 128), dim3(256), 0, stream>>>(logits_p, post, out, N, 0);
    k_softpool<<<dim3(B, T / 128), dim3(256), 0, stream>>>(logits_r, review, out, T, 64);
}

// Round 10
// 190.791 us; speedup vs baseline: 1.3051x; 1.3051x over previous
//
#include <hip/hip_runtime.h>
#include <hip/hip_bf16.h>
#include <cstdint>

#define DEV __device__ __forceinline__

constexpr int B = 64, T = 1024, N = 512, D = 64, K = 80;

typedef __attribute__((ext_vector_type(8))) short bf16x8;
typedef __attribute__((ext_vector_type(4))) float f32x4;

DEV float fast_tanh(float x) {
    x = fminf(fmaxf(x, -15.f), 15.f);
    float e = __expf(2.f * x);
    return (e - 1.f) / (e + 1.f);
}

DEV unsigned short f2bf(float f) {
    unsigned int u = __float_as_uint(f);
    unsigned int r = (u + 0x7fffu + ((u >> 16) & 1u)) >> 16;
    return (unsigned short)r;
}
DEV float bf2f(unsigned short s) {
    return __uint_as_float(((unsigned int)s) << 16);
}

// Fragment-native tiled layout for all bf16 intermediate buffers.
// off(row,col) = ((row/16)*(S/8) + col/8)*128 + (row%16)*8 + (col%8)
// => a wave's MFMA fragment load (rows base+lr, cols c0+lg*8) is a single
//    contiguous 1KB segment, and a 64-row x 64-col tile is a few contiguous
//    multi-KB runs (used by the v10 LDS staging). S8 = columns/8.
DEV size_t tix(size_t row, int col, int S8) {
    return (((row >> 4) * S8 + (size_t)(col >> 3)) << 7) + ((row & 15) << 3) + (col & 7);
}

#define MFMA(a, b, c) __builtin_amdgcn_mfma_f32_16x16x32_bf16((a), (b), (c), 0, 0, 0)

// ---------------------------------------------------------------------------
// Kernel A: M[b,t,:] = review[b,t,:] @ Wl, written as bf16 hi/lo pair (tiled)
__global__ __launch_bounds__(256) void k_matWl(const float* __restrict__ review,
                                               const float* __restrict__ Wl,
                                               unsigned short* __restrict__ Mhi,
                                               unsigned short* __restrict__ Mlo) {
    __shared__ float Wls[64][64];
    __shared__ float Rs[4][64];
    int tid = threadIdx.x;
    size_t base = (size_t)blockIdx.x * 256;
#pragma unroll
    for (int i = 0; i < 16; i++) { int e = tid + i * 256; Wls[e >> 6][e & 63] = Wl[e]; }
    Rs[tid >> 6][tid & 63] = review[base + tid];
    __syncthreads();
    int r = tid >> 6, c = tid & 63;
    float acc = 0.f;
#pragma unroll
    for (int d = 0; d < 64; d++) acc += Rs[r][d] * Wls[d][c];
    unsigned short h = f2bf(acc);
    size_t o = tix((size_t)blockIdx.x * 4 + r, c, 8);
    Mhi[o] = h;
    Mlo[o] = f2bf(acc - bf2f(h));
}

// ---------------------------------------------------------------------------
// Splitter: f32 -> bf16 hi/lo, elementwise, tiled-layout output (for post)
__global__ __launch_bounds__(256) void k_split(const float* __restrict__ X,
                                               unsigned short* __restrict__ Xhi,
                                               unsigned short* __restrict__ Xlo,
                                               int n4) {
    int i = blockIdx.x * 256 + threadIdx.x;
    if (i >= n4) return;
    float4 v = *reinterpret_cast<const float4*>(X + (size_t)i * 4);
    ushort4 h, lo;
    h.x = f2bf(v.x); lo.x = f2bf(v.x - bf2f(h.x));
    h.y = f2bf(v.y); lo.y = f2bf(v.y - bf2f(h.y));
    h.z = f2bf(v.z); lo.z = f2bf(v.z - bf2f(h.z));
    h.w = f2bf(v.w); lo.w = f2bf(v.w - bf2f(h.w));
    size_t o = tix((size_t)(i >> 4), (i & 15) * 4, 8);   // row = i*4/64, col = (i*4)%64
    *reinterpret_cast<ushort4*>(Xhi + o) = h;
    *reinterpret_cast<ushort4*>(Xlo + o) = lo;
}

// ---------------------------------------------------------------------------
// Kernel B: proj[b,k,s] = sum_d W[k,d] * X[b,s,d], bf16 hi/lo pair, tiled
__global__ __launch_bounds__(256) void k_proj(const float* __restrict__ W,
                                              const float* __restrict__ X,
                                              unsigned short* __restrict__ Phi,
                                              unsigned short* __restrict__ Plo, int S) {
    __shared__ float Ws[80][64];
    __shared__ float Xs[64][65];
    int tid = threadIdx.x, tx = tid & 63, ty = tid >> 6;
    int b = blockIdx.y, s0 = blockIdx.x * 64;
#pragma unroll
    for (int i = 0; i < 20; i++) { int e = tid + i * 256; Ws[e >> 6][e & 63] = W[e]; }
    const float* Xp = X + ((size_t)b * S + s0) * 64;
#pragma unroll
    for (int i = 0; i < 16; i++) { int e = tid + i * 256; Xs[e >> 6][e & 63] = Xp[e]; }
    __syncthreads();
    float acc[20];
#pragma unroll
    for (int kk = 0; kk < 20; kk++) acc[kk] = 0.f;
    for (int d = 0; d < 64; d += 4) {
        float x0 = Xs[tx][d], x1 = Xs[tx][d + 1], x2 = Xs[tx][d + 2], x3 = Xs[tx][d + 3];
#pragma unroll
        for (int kk = 0; kk < 20; kk++) {
            const float4 w = *reinterpret_cast<const float4*>(&Ws[ty * 20 + kk][d]);
            acc[kk] += w.x * x0 + w.y * x1 + w.z * x2 + w.w * x3;
        }
    }
    int S8 = S >> 3;
#pragma unroll
    for (int kk = 0; kk < 20; kk++) {
        size_t idx = tix((size_t)b * K + ty * 20 + kk, s0 + tx, S8);
        float v = acc[kk];
        unsigned short h = f2bf(v);
        Phi[idx] = h;
        Plo[idx] = f2bf(v - bf2f(h));
    }
}

// ---------------------------------------------------------------------------
// Fused HP v10: 256 thr = 4 waves; wave wv owns n-slice [nc0+16wv,+16).
// Per t-tile (16 tiles of 64): the BLOCK cooperatively stages the shared
// M-tile (16KB) + Rr-tile (20KB) into LDS once (36 x 1KB flat copies, 9 per
// wave; global loads issued before the barrier to hide latency under the
// previous tile's MFMAs). Fragments are then ds_read (conflict-free linear)
// instead of duplicated global loads: per-block global traffic halves
// (1152KB -> 576KB) with NO extra register state (v9's spill trap).
// No cross-wave reduction: each wave owns its slice across all tiles.
__global__ __launch_bounds__(256) void k_hp_fused(
    const unsigned short* __restrict__ Mhi, const unsigned short* __restrict__ Mlo,
    const unsigned short* __restrict__ PsH, const unsigned short* __restrict__ PsL,
    const unsigned short* __restrict__ Rhi, const unsigned short* __restrict__ Rlo,
    const unsigned short* __restrict__ Phi, const unsigned short* __restrict__ Plo,
    const float* __restrict__ whp, float* __restrict__ logits_p) {
    __shared__ __align__(16) unsigned short smem[23040];   // 46,080 B
    unsigned short* MH_l = smem;            // [64][64] tiled, 4096
    unsigned short* ML_l = smem + 4096;
    unsigned short* RH_l = smem + 8192;     // [80][64] tiled, 5120
    unsigned short* RL_l = smem + 13312;
    typedef unsigned short LtRow[72];
    LtRow* Lt = reinterpret_cast<LtRow*>(smem + 18432);    // [64][72]
    int b = blockIdx.x, nc0 = blockIdx.y * 64;
    int tid = threadIdx.x, l = tid & 63, wv = tid >> 6;
    int lr = l & 15, lg = l >> 4;

    // Preload own n-slice post fragments: loop-invariant.
    size_t prow = (size_t)b * N + nc0 + wv * 16 + lr;
    size_t p0 = tix(prow, lg * 8, 8), p1 = tix(prow, 32 + lg * 8, 8);
    bf16x8 pah0 = *reinterpret_cast<const bf16x8*>(PsH + p0);
    bf16x8 pah1 = *reinterpret_cast<const bf16x8*>(PsH + p1);
    bf16x8 pal0 = *reinterpret_cast<const bf16x8*>(PsL + p0);
    bf16x8 pal1 = *reinterpret_cast<const bf16x8*>(PsL + p1);

    f32x4 hp[5];
#pragma unroll
    for (int f = 0; f < 5; f++) hp[f] = (f32x4){0.f, 0.f, 0.f, 0.f};

    for (int tt = 0; tt < 16; tt++) {
        size_t m_base = ((size_t)b * T + tt * 64) * 64;    // M tile: 8KB contiguous
        bf16x8 tmp[9];
#pragma unroll
        for (int i = 0; i < 9; i++) {
            int c = wv + i * 4;
            const unsigned short* src;
            if (c < 8)       src = Mhi + m_base + c * 512;
            else if (c < 16) src = Mlo + m_base + (c - 8) * 512;
            else {
                int j = c - 16, jj = (j < 10) ? j : j - 10;
                int rg = jj >> 1, half = jj & 1;
                src = ((j < 10) ? Rhi : Rlo) +
                      ((size_t)(b * 5 + rg) * 128 + tt * 8) * 128 + half * 512;
            }
            tmp[i] = *reinterpret_cast<const bf16x8*>(src + l * 8);
        }
        __syncthreads();                    // prior tile's LDS reads done
#pragma unroll
        for (int i = 0; i < 9; i++) {
            int c = wv + i * 4;
            unsigned short* dst;
            if (c < 8)       dst = MH_l + c * 512;
            else if (c < 16) dst = ML_l + (c - 8) * 512;
            else {
                int j = c - 16, jj = (j < 10) ? j : j - 10;
                int rg = jj >> 1, half = jj & 1;
                dst = ((j < 10) ? RH_l : RL_l) + rg * 1024 + half * 512;
            }
            *reinterpret_cast<bf16x8*>(dst + l * 8) = tmp[i];
        }
        __syncthreads();                    // staged tile visible

        // phase 1 (swapped operands): L rows for own n-slice over 64 t.
#pragma unroll
        for (int tf = 0; tf < 4; tf++) {
            int o0 = tf * 1024 + lg * 128 + lr * 8;
            int o1 = tf * 1024 + (4 + lg) * 128 + lr * 8;
            bf16x8 mh0 = *reinterpret_cast<const bf16x8*>(MH_l + o0);
            bf16x8 mh1 = *reinterpret_cast<const bf16x8*>(MH_l + o1);
            bf16x8 ml0 = *reinterpret_cast<const bf16x8*>(ML_l + o0);
            bf16x8 ml1 = *reinterpret_cast<const bf16x8*>(ML_l + o1);
            f32x4 a = (f32x4){0.f, 0.f, 0.f, 0.f};
            a = MFMA(pah0, mh0, a);
            a = MFMA(pah0, ml0, a);
            a = MFMA(pal0, mh0, a);
            a = MFMA(pah1, mh1, a);
            a = MFMA(pah1, ml1, a);
            a = MFMA(pal1, mh1, a);
#pragma unroll
            for (int r = 0; r < 4; r++)
                Lt[wv * 16 + lg * 4 + r][tf * 16 + lr] = f2bf(fast_tanh(a[r]));
        }
        bf16x8 bt0 = *reinterpret_cast<const bf16x8*>(&Lt[wv * 16 + lr][lg * 8]);
        bf16x8 bt1 = *reinterpret_cast<const bf16x8*>(&Lt[wv * 16 + lr][32 + lg * 8]);
        // phase 2: hp[k] += Rr[k, t-tile] @ L (Rr from LDS)
#pragma unroll
        for (int kf = 0; kf < 5; kf++) {
            int o0 = kf * 1024 + lg * 128 + lr * 8;
            int o1 = kf * 1024 + (4 + lg) * 128 + lr * 8;
            bf16x8 rh0 = *reinterpret_cast<const bf16x8*>(RH_l + o0);
            bf16x8 rh1 = *reinterpret_cast<const bf16x8*>(RH_l + o1);
            bf16x8 rl0 = *reinterpret_cast<const bf16x8*>(RL_l + o0);
            bf16x8 rl1 = *reinterpret_cast<const bf16x8*>(RL_l + o1);
            hp[kf] = MFMA(rh0, bt0, hp[kf]);
            hp[kf] = MFMA(rl0, bt0, hp[kf]);
            hp[kf] = MFMA(rh1, bt1, hp[kf]);
            hp[kf] = MFMA(rl1, bt1, hp[kf]);
        }
    }

    // epilogue: own n-slice, no cross-wave reduction needed.
    int n = nc0 + wv * 16 + lr;
    float partial = 0.f;
#pragma unroll
    for (int kf = 0; kf < 5; kf++)
#pragma unroll
        for (int r = 0; r < 4; r++) {
            int k = kf * 16 + lg * 4 + r;
            size_t idx = tix((size_t)b * K + k, n, 64);
            float pp = bf2f(Phi[idx]) + bf2f(Plo[idx]);
            partial += whp[k] * fast_tanh(pp + hp[kf][r]);
        }
    partial += __shfl_xor(partial, 16);
    partial += __shfl_xor(partial, 32);
    if (lg == 0) logits_p[(size_t)b * N + n] = partial;
}

// ---------------------------------------------------------------------------
// Fused HR v10: 256 thr = 4 waves; wave wv owns t-slice [tc0+16wv,+16).
// Per n-tile (8 tiles of 64): block stages Ps-tile (16KB) + Pp-tile (20KB)
// into LDS once; fragments ds_read. Per-block global traffic 576KB -> 288KB.
__global__ __launch_bounds__(256) void k_hr_fused(
    const unsigned short* __restrict__ Mhi, const unsigned short* __restrict__ Mlo,
    const unsigned short* __restrict__ PsH, const unsigned short* __restrict__ PsL,
    const unsigned short* __restrict__ Phi, const unsigned short* __restrict__ Plo,
    const unsigned short* __restrict__ Rhi, const unsigned short* __restrict__ Rlo,
    const float* __restrict__ whr, float* __restrict__ logits_r) {
    __shared__ __align__(16) unsigned short smem[23040];   // 46,080 B
    unsigned short* PsH_l = smem;           // [64][64] tiled, 4096
    unsigned short* PsL_l = smem + 4096;
    unsigned short* PpH_l = smem + 8192;    // [80][64] tiled, 5120
    unsigned short* PpL_l = smem + 13312;
    typedef unsigned short LtRow[72];
    LtRow* Lt = reinterpret_cast<LtRow*>(smem + 18432);    // [64][72]
    int b = blockIdx.x, tc0 = blockIdx.y * 64;
    int tid = threadIdx.x, l = tid & 63, wv = tid >> 6;
    int lr = l & 15, lg = l >> 4;

    // Preload own t-slice M fragments: loop-invariant.
    size_t mrow = (size_t)b * T + tc0 + wv * 16 + lr;
    size_t m0 = tix(mrow, lg * 8, 8), m1 = tix(mrow, 32 + lg * 8, 8);
    bf16x8 mh0 = *reinterpret_cast<const bf16x8*>(Mhi + m0);
    bf16x8 mh1 = *reinterpret_cast<const bf16x8*>(Mhi + m1);
    bf16x8 ml0 = *reinterpret_cast<const bf16x8*>(Mlo + m0);
    bf16x8 ml1 = *reinterpret_cast<const bf16x8*>(Mlo + m1);

    f32x4 hr[5];
#pragma unroll
    for (int f = 0; f < 5; f++) hr[f] = (f32x4){0.f, 0.f, 0.f, 0.f};

    for (int nt = 0; nt < 8; nt++) {
        size_t ps_base = ((size_t)b * N + nt * 64) * 64;   // Ps tile: 8KB contiguous
        bf16x8 tmp[9];
#pragma unroll
        for (int i = 0; i < 9; i++) {
            int c = wv + i * 4;
            const unsigned short* src;
            if (c < 8)       src = PsH + ps_base + c * 512;
            else if (c < 16) src = PsL + ps_base + (c - 8) * 512;
            else {
                int j = c - 16, jj = (j < 10) ? j : j - 10;
                int rg = jj >> 1, half = jj & 1;
                src = ((j < 10) ? Phi : Plo) +
                      ((size_t)(b * 5 + rg) * 64 + nt * 8) * 128 + half * 512;
            }
            tmp[i] = *reinterpret_cast<const bf16x8*>(src + l * 8);
        }
        __syncthreads();                    // prior tile's LDS reads done
#pragma unroll
        for (int i = 0; i < 9; i++) {
            int c = wv + i * 4;
            unsigned short* dst;
            if (c < 8)       dst = PsH_l + c * 512;
            else if (c < 16) dst = PsL_l + (c - 8) * 512;
            else {
                int j = c - 16, jj = (j < 10) ? j : j - 10;
                int rg = jj >> 1, half = jj & 1;
                dst = ((j < 10) ? PpH_l : PpL_l) + rg * 1024 + half * 512;
            }
            *reinterpret_cast<bf16x8*>(dst + l * 8) = tmp[i];
        }
        __syncthreads();                    // staged tile visible

        // phase 1: L rows for own t-slice over 64 n (Ps from LDS).
#pragma unroll
        for (int nf = 0; nf < 4; nf++) {
            int o0 = nf * 1024 + lg * 128 + lr * 8;
            int o1 = nf * 1024 + (4 + lg) * 128 + lr * 8;
            bf16x8 ph0 = *reinterpret_cast<const bf16x8*>(PsH_l + o0);
            bf16x8 ph1 = *reinterpret_cast<const bf16x8*>(PsH_l + o1);
            bf16x8 pl0 = *reinterpret_cast<const bf16x8*>(PsL_l + o0);
            bf16x8 pl1 = *reinterpret_cast<const bf16x8*>(PsL_l + o1);
            f32x4 a = (f32x4){0.f, 0.f, 0.f, 0.f};
            a = MFMA(mh0, ph0, a);
            a = MFMA(mh0, pl0, a);
            a = MFMA(ml0, ph0, a);
            a = MFMA(mh1, ph1, a);
            a = MFMA(mh1, pl1, a);
            a = MFMA(ml1, ph1, a);
#pragma unroll
            for (int r = 0; r < 4; r++)
                Lt[wv * 16 + lg * 4 + r][nf * 16 + lr] = f2bf(fast_tanh(a[r]));
        }
        bf16x8 bt0 = *reinterpret_cast<const bf16x8*>(&Lt[wv * 16 + lr][lg * 8]);
        bf16x8 bt1 = *reinterpret_cast<const bf16x8*>(&Lt[wv * 16 + lr][32 + lg * 8]);
        // phase 2: hr[k] += Pp[k, n-tile] @ L (Pp from LDS)
#pragma unroll
        for (int kf = 0; kf < 5; kf++) {
            int o0 = kf * 1024 + lg * 128 + lr * 8;
            int o1 = kf * 1024 + (4 + lg) * 128 + lr * 8;
            bf16x8 qh0 = *reinterpret_cast<const bf16x8*>(PpH_l + o0);
            bf16x8 qh1 = *reinterpret_cast<const bf16x8*>(PpH_l + o1);
            bf16x8 ql0 = *reinterpret_cast<const bf16x8*>(PpL_l + o0);
            bf16x8 ql1 = *reinterpret_cast<const bf16x8*>(PpL_l + o1);
            hr[kf] = MFMA(qh0, bt0, hr[kf]);
            hr[kf] = MFMA(ql0, bt0, hr[kf]);
            hr[kf] = MFMA(qh1, bt1, hr[kf]);
            hr[kf] = MFMA(ql1, bt1, hr[kf]);
        }
    }

    // epilogue: own t-slice.
    int t = tc0 + wv * 16 + lr;
    float partial = 0.f;
#pragma unroll
    for (int kf = 0; kf < 5; kf++)
#pragma unroll
        for (int r = 0; r < 4; r++) {
            int k = kf * 16 + lg * 4 + r;
            size_t idx = tix((size_t)b * K + k, t, 128);
            float rr = bf2f(Rhi[idx]) + bf2f(Rlo[idx]);
            partial += whr[k] * fast_tanh(rr + hr[kf][r]);
        }
    partial += __shfl_xor(partial, 16);
    partial += __shfl_xor(partial, 32);
    if (lg == 0) logits_r[(size_t)b * T + t] = partial;
}

// ---------------------------------------------------------------------------
// Zero the output buffer (for atomic pooled accumulation). grid = B*128/256.
__global__ __launch_bounds__(256) void k_zero(float* __restrict__ out) {
    out[(size_t)blockIdx.x * 256 + threadIdx.x] = 0.f;
}

// ---------------------------------------------------------------------------
// Kernel F/G: softmax over S, then out[b, off+d] += sum_{s in chunk} sm[s]*X[b,s,d].
__global__ __launch_bounds__(256) void k_softpool(const float* __restrict__ logits,
                                                  const float* __restrict__ X,
                                                  float* __restrict__ out, int S, int off) {
    __shared__ float sm[1024];
    __shared__ float red[256];
    int b = blockIdx.x, tid = threadIdx.x;
    int c0 = blockIdx.y * 128;
    for (int i = tid; i < S; i += 256) sm[i] = logits[(size_t)b * S + i];
    __syncthreads();
    float m = -1e30f;
    for (int i = tid; i < S; i += 256) m = fmaxf(m, sm[i]);
    red[tid] = m;
    __syncthreads();
    for (int s = 128; s > 0; s >>= 1) {
        if (tid < s) red[tid] = fmaxf(red[tid], red[tid + s]);
        __syncthreads();
    }
    float mx = red[0];
    __syncthreads();
    float psum = 0.f;
    for (int i = tid; i < S; i += 256) {
        float e = __expf(sm[i] - mx);
        sm[i] = e;
        psum += e;
    }
    red[tid] = psum;
    __syncthreads();
    for (int s = 128; s > 0; s >>= 1) {
        if (tid < s) red[tid] += red[tid + s];
        __syncthreads();
    }
    float inv = 1.f / red[0];
    __syncthreads();
    int d = tid & 63, g = tid >> 6;
    float acc = 0.f;
    for (int n = c0 + g; n < c0 + 128; n += 4) acc += sm[n] * X[((size_t)b * S + n) * 64 + d];
    red[tid] = acc * inv;
    __syncthreads();
    if (g == 0)
        atomicAdd(&out[(size_t)b * 128 + off + d],
                  red[d] + red[64 + d] + red[128 + d] + red[192 + d]);
}

// ---------------------------------------------------------------------------
extern "C" void kernel_launch(void* const* d_in, const int* in_sizes, int n_in,
                              void* d_out, int out_size, void* d_ws, size_t ws_size,
                              hipStream_t stream) {
    const float* review = (const float*)d_in[0];
    const float* post   = (const float*)d_in[1];
    const float* Wl     = (const float*)d_in[2];
    const float* Wr     = (const float*)d_in[3];
    const float* Wp     = (const float*)d_in[4];
    const float* whr    = (const float*)d_in[5];
    const float* whp    = (const float*)d_in[6];
    float* out = (float*)d_out;

    char* p = (char*)d_ws;
    unsigned short* Mhi = (unsigned short*)p;  p += (size_t)B * T * D * 2;
    unsigned short* Mlo = (unsigned short*)p;  p += (size_t)B * T * D * 2;
    unsigned short* PsH = (unsigned short*)p;  p += (size_t)B * N * D * 2;
    unsigned short* PsL = (unsigned short*)p;  p += (size_t)B * N * D * 2;
    unsigned short* Rhi = (unsigned short*)p;  p += (size_t)B * K * T * 2;
    unsigned short* Rlo = (unsigned short*)p;  p += (size_t)B * K * T * 2;
    unsigned short* Phi = (unsigned short*)p;  p += (size_t)B * K * N * 2;
    unsigned short* Plo = (unsigned short*)p;  p += (size_t)B * K * N * 2;
    float* logits_p = (float*)p;        p += (size_t)B * N * 4;
    float* logits_r = (float*)p;        p += (size_t)B * T * 4;

    k_matWl<<<dim3(B * T / 4), dim3(256), 0, stream>>>(review, Wl, Mhi, Mlo);
    k_split<<<dim3(B * N * D / 4 / 256), dim3(256), 0, stream>>>(post, PsH, PsL, B * N * D / 4);
    k_proj<<<dim3(T / 64, B), dim3(256), 0, stream>>>(Wr, review, Rhi, Rlo, T);
    k_proj<<<dim3(N / 64, B), dim3(256), 0, stream>>>(Wp, post, Phi, Plo, N);
    k_zero<<<dim3(B * 128 / 256), dim3(256), 0, stream>>>(out);
    k_hp_fused<<<dim3(B, N / 64), dim3(256), 0, stream>>>(Mhi, Mlo, PsH, PsL, Rhi, Rlo,
                                                          Phi, Plo, whp, logits_p);
    k_hr_fused<<<dim3(B, T / 64), dim3(256), 0, stream>>>(Mhi, Mlo, PsH, PsL, Phi, Plo,
                                                          Rhi, Rlo, whr, logits_r);
    k_softpool<<<dim3(B, N / 128), dim3(256), 0, stream>>>(logits_p, post, out, N, 0);
    k_softpool<<<dim3(B, T / 128), dim3(256), 0, stream>>>(logits_r, review, out, T, 64);
}